// Round 16
// baseline (490.519 us; speedup 1.0000x reference)
//
#include <hip/hip_runtime.h>

#define BATCH 16384
#define RT    32        // batch rows per block -> 512 blocks -> 2 blocks/CU

typedef unsigned short u16;
typedef __attribute__((ext_vector_type(8))) short short8;
typedef __attribute__((ext_vector_type(8))) _Float16 f16x8;
typedef __attribute__((ext_vector_type(4))) float f32x4;

// ---------- fp16 helpers ----------
__device__ __forceinline__ u16 f2h(float x) {
    union { _Float16 h; u16 u; } c; c.h = (_Float16)x; return c.u;
}
__device__ __forceinline__ float h2f(u16 b) {
    union { u16 u; _Float16 h; } c; c.u = b; return (float)c.h;
}
__device__ __forceinline__ unsigned int pk2(float a, float b) {
    union { __attribute__((ext_vector_type(2))) __fp16 v; unsigned int u; } c;
    c.v = __builtin_amdgcn_cvt_pkrtz(a, b);
    return c.u;
}
// 16-lane sum via DPP (verified R9/R10)
__device__ __forceinline__ float red16(float x) {
    x += __builtin_bit_cast(float, __builtin_amdgcn_update_dpp(
             0, __builtin_bit_cast(int, x), 0xB1, 0xF, 0xF, true));
    x += __builtin_bit_cast(float, __builtin_amdgcn_update_dpp(
             0, __builtin_bit_cast(int, x), 0x4E, 0xF, 0xF, true));
    x += __builtin_bit_cast(float, __builtin_amdgcn_update_dpp(
             0, __builtin_bit_cast(int, x), 0x124, 0xF, 0xF, true));
    x += __builtin_bit_cast(float, __builtin_amdgcn_update_dpp(
             0, __builtin_bit_cast(int, x), 0x128, 0xF, 0xF, true));
    return x;
}

// ================= weight pre-pack kernels (single fp16) =================
// STRICT premask k <= v-2; newest possible parent k=v-1 handled in-kernel
// as a VALU rank-1 term (enables lazy Y finalize + cross-step pipelining).
__global__ void prep_w1(const float* __restrict__ W1, const int* __restrict__ G,
                        u16* __restrict__ P) {
    int idx = blockIdx.x * 256 + threadIdx.x;   // 64*64*256 exactly
    int n = idx & 255;
    int k = (idx >> 8) & 63;
    int v = idx >> 14;
    float w = (k + 1 < v && G[k * 64 + v] > 0) ? W1[((size_t)v * 65 + k) * 256 + n] : 0.0f;
    P[(((size_t)(v * 8 + (k >> 3)) * 256 + n) << 3) + (k & 7)] = f2h(w);
}
// Wp[v][n] = G[v-1][v] ? W1[v][k=v-1][n] : 0   (fp16, 32 KB, L2-resident)
__global__ void prep_wp1(const float* __restrict__ W1, const int* __restrict__ G,
                         u16* __restrict__ P) {
    int n = threadIdx.x;
    int v = blockIdx.x;
    float w = (v >= 1 && G[(v - 1) * 64 + v] > 0)
                  ? W1[((size_t)v * 65 + (v - 1)) * 256 + n] : 0.0f;
    P[v * 256 + n] = f2h(w);
}
__global__ void prep_w2(const float* __restrict__ W2, u16* __restrict__ P) {
    int idx = blockIdx.x * 256 + threadIdx.x;   // 64*256*128 exactly
    int n = idx & 127;
    int k = (idx >> 7) & 255;
    int v = idx >> 15;
    P[(((size_t)(v * 32 + (k >> 3)) * 128 + n) << 3) + (k & 7)] =
        f2h(W2[((size_t)v * 256 + k) * 128 + n]);
}

// ================= persistent fused kernel: wave-specialized =================
// 1024 threads = 16 waves. Waves 0..7 (group A): phase2(v) + layer3 + yp.
// Waves 8..15 (group B): epilogue(v)->h1 (segment B) and phase1-MFMA(v+1)
// (segment A). No weight fragment is loaded twice -> per-CU global traffic
// identical to the 8-wave kernel, at 2x the waves/SIMD (8 = HW max).
#define AST   72     // Y-tile stride (u16): 144B = 16 mod 128
#define H1ST  264    // h1 stride (u16): 528B = 16 mod 128
#define YOST  68     // Yout stride (f32)

__global__ __launch_bounds__(1024, 8)
void sen_fused(const float* __restrict__ U,
               const u16* __restrict__ P1, const u16* __restrict__ P2,
               const u16* __restrict__ Wp,
               const float* __restrict__ W1, const float* __restrict__ b1,
               const float* __restrict__ b2, const float* __restrict__ W3,
               const float* __restrict__ b3, float* __restrict__ Y)
{
    __shared__ __attribute__((aligned(16))) u16 Ay[RT * AST];
    __shared__ __attribute__((aligned(16))) u16 h1[RT * H1ST];
    __shared__ __attribute__((aligned(16))) float yp[RT][12];  // [row][cg]+pad
    __shared__ __attribute__((aligned(16))) float Yout[RT * YOST];

    const int tid  = threadIdx.x;
    const int row0 = blockIdx.x * RT;

    // zero-init Y tile AND yp (v=0 reads yp; must be finite)
    {
        short8 z = {0,0,0,0,0,0,0,0};
        for (int i = tid; i < (RT * AST) / 8; i += 1024)
            *(short8*)&Ay[i * 8] = z;
        if (tid < RT * 12) ((float*)yp)[tid] = 0.0f;
    }
    __syncthreads();

    const int w  = tid >> 6, l = tid & 63;
    const int lr = l & 15,  lk = l >> 4;
    const bool grpA = (w < 8);
    const int g = w & 7;    // A: col group (16 cols) / B: dim group (32 dims)

    // group-B persistent state: acc1(v) = W1_strict(v) @ Y  (b1 added at use)
    f32x4 acc1[2][2];
    #pragma unroll
    for (int nj = 0; nj < 2; ++nj)
        #pragma unroll
        for (int ni = 0; ni < 2; ++ni) acc1[nj][ni] = (f32x4){0.f, 0.f, 0.f, 0.f};

    #pragma unroll 1
    for (int v = 0; v < 64; ++v) {
        // ======== SEGMENT B (group B): finish phase 1 of step v ========
        if (!grpA) {
            f32x4 b1v[2], w64v[2], wpv[2];
            #pragma unroll
            for (int ni = 0; ni < 2; ++ni) {
                const int dim = g * 32 + ni * 16 + lk * 4;
                b1v[ni]  = *(const f32x4*)(b1 + v * 256 + dim);
                w64v[ni] = *(const f32x4*)(W1 + ((size_t)v * 65 + 64) * 256 + dim);
                const u16* wp = &Wp[v * 256 + dim];
                wpv[ni] = (f32x4){h2f(wp[0]), h2f(wp[1]), h2f(wp[2]), h2f(wp[3])};
            }
            float u_c[2], yprev[2];
            const float b3p = (v > 0) ? b3[v - 1] : 0.0f;
            #pragma unroll
            for (int nj = 0; nj < 2; ++nj) {
                u_c[nj] = U[(size_t)(row0 + nj * 16 + lr) * 64 + v];
                const int row = nj * 16 + lr;
                const f32x4 a = *(const f32x4*)&yp[row][0];
                const f32x4 b = *(const f32x4*)&yp[row][4];
                yprev[nj] = b3p + a[0] + a[1] + a[2] + a[3] + b[0] + b[1] + b[2] + b[3];
            }
            if (v > 0 && w == 8 && lk == 0) {   // lazy finalize col v-1
                Ay[lr * AST + (v - 1)]        = f2h(yprev[0]);
                Ay[(16 + lr) * AST + (v - 1)] = f2h(yprev[1]);
                Yout[lr * YOST + (v - 1)]        = yprev[0];
                Yout[(16 + lr) * YOST + (v - 1)] = yprev[1];
            }
            #pragma unroll
            for (int nj = 0; nj < 2; ++nj) {
                const int brow = nj * 16 + lr;
                #pragma unroll
                for (int ni = 0; ni < 2; ++ni) {
                    float x[4];
                    #pragma unroll
                    for (int r = 0; r < 4; ++r)
                        x[r] = fmaxf(acc1[nj][ni][r] + b1v[ni][r]
                                     + u_c[nj] * w64v[ni][r]
                                     + yprev[nj] * wpv[ni][r], 0.0f);
                    unsigned long long pk = (unsigned long long)pk2(x[0], x[1])
                                          | ((unsigned long long)pk2(x[2], x[3]) << 32);
                    *(unsigned long long*)&h1[brow * H1ST + g * 32 + ni * 16 + lk * 4] = pk;
                }
            }
        }
        __syncthreads();   // B1: h1 + Ay col v-1 visible

        // ======== SEGMENT A: groupA=phase2(v) || groupB=phase1-MFMA(v+1) ========
        if (grpA) {
            f32x4 acc2[2];
            acc2[0] = (f32x4){0.f, 0.f, 0.f, 0.f};
            acc2[1] = acc2[0];
            const float b2c = b2[v * 128 + g * 16 + lr];
            const float w3c = W3[v * 128 + g * 16 + lr];
            #pragma unroll
            for (int kt = 0; kt < 8; ++kt) {
                const f16x8 Bf = *(const f16x8*)&P2[
                    (((size_t)(v * 32 + kt * 4 + lk) * 128) + g * 16 + lr) << 3];
                #pragma unroll
                for (int mi = 0; mi < 2; ++mi) {
                    const f16x8 Hf = *(const f16x8*)&h1[(mi * 16 + lr) * H1ST + kt * 32 + lk * 8];
                    acc2[mi] = __builtin_amdgcn_mfma_f32_16x16x32_f16(Hf, Bf, acc2[mi], 0, 0, 0);
                }
            }
            #pragma unroll
            for (int mi = 0; mi < 2; ++mi) {
                float s0 = red16(fmaxf(acc2[mi][0] + b2c, 0.0f) * w3c);
                float s1 = red16(fmaxf(acc2[mi][1] + b2c, 0.0f) * w3c);
                float s2 = red16(fmaxf(acc2[mi][2] + b2c, 0.0f) * w3c);
                float s3 = red16(fmaxf(acc2[mi][3] + b2c, 0.0f) * w3c);
                if (lr == 0) {
                    const int row = mi * 16 + lk * 4;
                    yp[row + 0][g] = s0;
                    yp[row + 1][g] = s1;
                    yp[row + 2][g] = s2;
                    yp[row + 3][g] = s3;
                }
            }
        } else {
            // phase 1 MFMA for step v+1 (reads Ay cols <= v-1 only: strict mask)
            #pragma unroll
            for (int nj = 0; nj < 2; ++nj)
                #pragma unroll
                for (int ni = 0; ni < 2; ++ni) acc1[nj][ni] = (f32x4){0.f, 0.f, 0.f, 0.f};
            const int vn = v + 1;
            if (vn < 64) {
                #pragma unroll
                for (int kt = 0; kt < 2; ++kt) {
                    f16x8 Yf[2];
                    #pragma unroll
                    for (int nj = 0; nj < 2; ++nj)
                        Yf[nj] = *(const f16x8*)&Ay[(nj * 16 + lr) * AST + kt * 32 + lk * 8];
                    #pragma unroll
                    for (int ni = 0; ni < 2; ++ni) {
                        const f16x8 Wf = *(const f16x8*)&P1[
                            (((size_t)(vn * 8 + kt * 4 + lk) * 256) + g * 32 + ni * 16 + lr) << 3];
                        #pragma unroll
                        for (int nj = 0; nj < 2; ++nj)
                            acc1[nj][ni] = __builtin_amdgcn_mfma_f32_16x16x32_f16(Wf, Yf[nj], acc1[nj][ni], 0, 0, 0);
                    }
                }
            }
        }
        __syncthreads();   // B2: yp complete; h1 free for next step
    }

    // ---- y_63 from final yp (fenced by last B2), then coalesced f32 store ----
    if (w == 8 && lk == 0) {
        #pragma unroll
        for (int nj = 0; nj < 2; ++nj) {
            const int row = nj * 16 + lr;
            const f32x4 a = *(const f32x4*)&yp[row][0];
            const f32x4 b = *(const f32x4*)&yp[row][4];
            Yout[row * YOST + 63] =
                b3[63] + a[0] + a[1] + a[2] + a[3] + b[0] + b[1] + b[2] + b[3];
        }
    }
    __syncthreads();
    if (tid < RT * 16) {
        const int row = tid >> 4, c4 = (tid & 15) * 4;
        *(float4*)(Y + (size_t)(row0 + row) * 64 + c4) = *(float4*)&Yout[row * YOST + c4];
    }
}

extern "C" void kernel_launch(void* const* d_in, const int* in_sizes, int n_in,
                              void* d_out, int out_size, void* d_ws, size_t ws_size,
                              hipStream_t stream) {
    // inputs: X, U, causal_graph, W1, b1, W2, b2, W3, b3  (X never feeds the recursion)
    const float* U  = (const float*)d_in[1];
    const int*   G  = (const int*)  d_in[2];
    const float* W1 = (const float*)d_in[3];
    const float* b1 = (const float*)d_in[4];
    const float* W2 = (const float*)d_in[5];
    const float* b2 = (const float*)d_in[6];
    const float* W3 = (const float*)d_in[7];
    const float* b3 = (const float*)d_in[8];
    float* Y = (float*)d_out;

    const size_t S1 = (size_t)64 * 64 * 256;     // u16, packed strict W1
    const size_t S2 = (size_t)64 * 256 * 128;    // u16, packed W2
    u16* P1 = (u16*)d_ws;
    u16* P2 = P1 + S1;
    u16* Wp = P2 + S2;                           // 64*256 u16

    prep_w1<<<(64 * 64 * 256) / 256, 256, 0, stream>>>(W1, G, P1);
    prep_w2<<<(64 * 256 * 128) / 256, 256, 0, stream>>>(W2, P2);
    prep_wp1<<<64, 256, 0, stream>>>(W1, G, Wp);
    sen_fused<<<BATCH / RT, 1024, 0, stream>>>(U, P1, P2, Wp, W1, b1, b2, W3, b3, Y);
}

// Round 17
// 214.175 us; speedup vs baseline: 2.2903x; 2.2903x over previous
//
#include <hip/hip_runtime.h>

#define BATCH 16384
#define RT    32        // batch rows per block -> 512 blocks -> 2 blocks/CU

typedef unsigned short u16;
typedef __attribute__((ext_vector_type(8))) short short8;
typedef __attribute__((ext_vector_type(8))) _Float16 f16x8;
typedef __attribute__((ext_vector_type(4))) float f32x4;

// ---------- fp16 helpers ----------
__device__ __forceinline__ u16 f2h(float x) {
    union { _Float16 h; u16 u; } c; c.h = (_Float16)x; return c.u;
}
__device__ __forceinline__ float h2f(u16 b) {
    union { u16 u; _Float16 h; } c; c.u = b; return (float)c.h;
}
__device__ __forceinline__ unsigned int pk2(float a, float b) {
    union { __attribute__((ext_vector_type(2))) __fp16 v; unsigned int u; } c;
    c.v = __builtin_amdgcn_cvt_pkrtz(a, b);
    return c.u;
}
// 16-lane sum via DPP (verified R9/R10)
__device__ __forceinline__ float red16(float x) {
    x += __builtin_bit_cast(float, __builtin_amdgcn_update_dpp(
             0, __builtin_bit_cast(int, x), 0xB1, 0xF, 0xF, true));
    x += __builtin_bit_cast(float, __builtin_amdgcn_update_dpp(
             0, __builtin_bit_cast(int, x), 0x4E, 0xF, 0xF, true));
    x += __builtin_bit_cast(float, __builtin_amdgcn_update_dpp(
             0, __builtin_bit_cast(int, x), 0x124, 0xF, 0xF, true));
    x += __builtin_bit_cast(float, __builtin_amdgcn_update_dpp(
             0, __builtin_bit_cast(int, x), 0x128, 0xF, 0xF, true));
    return x;
}

// ================= weight pre-pack kernels (single fp16) =================
// STRICT premask k <= v-2; newest possible parent k=v-1 handled in-kernel
// as a VALU rank-1 term (enables lazy Y finalize + cross-step pipelining).
__global__ void prep_w1(const float* __restrict__ W1, const int* __restrict__ G,
                        u16* __restrict__ P) {
    int idx = blockIdx.x * 256 + threadIdx.x;   // 64*64*256 exactly
    int n = idx & 255;
    int k = (idx >> 8) & 63;
    int v = idx >> 14;
    float w = (k + 1 < v && G[k * 64 + v] > 0) ? W1[((size_t)v * 65 + k) * 256 + n] : 0.0f;
    P[(((size_t)(v * 8 + (k >> 3)) * 256 + n) << 3) + (k & 7)] = f2h(w);
}
// Wp[v][n] = G[v-1][v] ? W1[v][k=v-1][n] : 0   (fp16, 32 KB, L2-resident)
__global__ void prep_wp1(const float* __restrict__ W1, const int* __restrict__ G,
                         u16* __restrict__ P) {
    int n = threadIdx.x;
    int v = blockIdx.x;
    float w = (v >= 1 && G[(v - 1) * 64 + v] > 0)
                  ? W1[((size_t)v * 65 + (v - 1)) * 256 + n] : 0.0f;
    P[v * 256 + n] = f2h(w);
}
__global__ void prep_w2(const float* __restrict__ W2, u16* __restrict__ P) {
    int idx = blockIdx.x * 256 + threadIdx.x;   // 64*256*128 exactly
    int n = idx & 127;
    int k = (idx >> 7) & 255;
    int v = idx >> 15;
    P[(((size_t)(v * 32 + (k >> 3)) * 128 + n) << 3) + (k & 7)] =
        f2h(W2[((size_t)v * 256 + k) * 128 + n]);
}

// ================= persistent fused kernel =================
// R15 structure (cross-step pipeline, 2 barriers/step) + VALU diet:
// v-invariant lane offsets precomputed once; per-step only scalar bases
// advance. U tile staged in LDS once.
#define AST   72     // Y-tile stride (u16): 144B = 16 mod 128
#define H1ST  264    // h1 stride (u16): 528B = 16 mod 128
#define YOST  68     // Yout stride (f32)
#define UST   68     // U-tile stride (f32)

__global__ __launch_bounds__(512, 4)
void sen_fused(const float* __restrict__ U,
               const u16* __restrict__ P1, const u16* __restrict__ P2,
               const u16* __restrict__ Wp,
               const float* __restrict__ W1, const float* __restrict__ b1,
               const float* __restrict__ b2, const float* __restrict__ W3,
               const float* __restrict__ b3, float* __restrict__ Y)
{
    __shared__ __attribute__((aligned(16))) u16 Ay[RT * AST];
    __shared__ __attribute__((aligned(16))) u16 h1[RT * H1ST];
    __shared__ __attribute__((aligned(16))) float yp[RT][12];  // [row][cg]+pad
    __shared__ __attribute__((aligned(16))) float Yout[RT * YOST];
    __shared__ __attribute__((aligned(16))) float Ut[RT * UST];

    const int tid  = threadIdx.x;
    const int row0 = blockIdx.x * RT;

    // zero-init Y tile + yp; stage U tile (coalesced, once)
    {
        short8 z = {0,0,0,0,0,0,0,0};
        for (int i = tid; i < (RT * AST) / 8; i += 512)
            *(short8*)&Ay[i * 8] = z;
        if (tid < RT * 12) ((float*)yp)[tid] = 0.0f;
        const int row = tid >> 4, c4 = (tid & 15) * 4;
        *(f32x4*)&Ut[row * UST + c4] =
            *(const f32x4*)(U + (size_t)(row0 + row) * 64 + c4);
    }
    __syncthreads();

    const int w  = tid >> 6, l = tid & 63;
    const int lr = l & 15,  lk = l >> 4;
    const int mg = w;   // phase 1: dim group (32 dims, W1 read once/block)
    const int cg = w;   // phase 2: col group (16 cols, W2 read once/block)

    // ---- v-invariant lane offsets (elements), computed ONCE ----
    int o_p1[2][2], o_p2[8];
    #pragma unroll
    for (int kt = 0; kt < 2; ++kt)
        #pragma unroll
        for (int ni = 0; ni < 2; ++ni)
            o_p1[kt][ni] = (((kt * 4 + lk) * 256) + mg * 32 + ni * 16 + lr) << 3;
    #pragma unroll
    for (int kt = 0; kt < 8; ++kt)
        o_p2[kt] = (((kt * 4 + lk) * 128) + cg * 16 + lr) << 3;
    const int dimc  = mg * 32 + lk * 4;   // + ni*16
    const int colc  = cg * 16 + lr;
    const int urow0 = lr * UST, urow1 = (16 + lr) * UST;

    // ---- bootstrap params for v=0; acc1 pre-initialized with b1 ----
    f32x4 acc1[2][2], w64v[2], wpv[2];
    float u_c[2], b2c, w3c, b3p;
    {
        #pragma unroll
        for (int ni = 0; ni < 2; ++ni) {
            const int dim = dimc + ni * 16;
            const f32x4 b1v = *(const f32x4*)(b1 + dim);
            acc1[0][ni] = b1v;          // strict mask(0) is empty -> no MFMA
            acc1[1][ni] = b1v;
            w64v[ni] = *(const f32x4*)(W1 + (size_t)64 * 256 + dim);
            const u16* wp = &Wp[dim];
            wpv[ni] = (f32x4){h2f(wp[0]), h2f(wp[1]), h2f(wp[2]), h2f(wp[3])};
        }
        u_c[0] = Ut[urow0];
        u_c[1] = Ut[urow1];
        b2c = b2[colc];
        w3c = W3[colc];
        b3p = 0.0f;   // y_{-1} unused (wpv(0)=0), just needs to be finite
    }

    #pragma unroll 1
    for (int v = 0; v < 64; ++v) {
        // per-step scalar bases (SGPR adds only)
        const u16*   P1v  = P1 + (size_t)(v + 1) * 16384;   // used for v+1
        const u16*   P2v  = P2 + (size_t)v * 32768;
        const float* b1p  = b1 + (v + 1) * 256;
        const float* w64p = W1 + ((size_t)(v + 1) * 65 + 64) * 256;
        const u16*   wpp  = Wp + (v + 1) * 256;
        const float* b2p  = b2 + (v + 1) * 128;
        const float* W3p  = W3 + (v + 1) * 128;

        // ======== SEGMENT B: finish phase 1 of step v ========
        float yprev[2];
        #pragma unroll
        for (int nj = 0; nj < 2; ++nj) {
            const int row = nj * 16 + lr;
            const f32x4 a = *(const f32x4*)&yp[row][0];
            const f32x4 b = *(const f32x4*)&yp[row][4];
            yprev[nj] = b3p + a[0] + a[1] + a[2] + a[3] + b[0] + b[1] + b[2] + b[3];
        }
        if (v > 0 && w == 0 && lk == 0) {   // lazy finalize col v-1
            Ay[lr * AST + (v - 1)]        = f2h(yprev[0]);
            Ay[(16 + lr) * AST + (v - 1)] = f2h(yprev[1]);
            Yout[lr * YOST + (v - 1)]        = yprev[0];
            Yout[(16 + lr) * YOST + (v - 1)] = yprev[1];
        }
        // epilogue: acc1 holds (W1_strict @ Y + b1); add rank-1 terms, relu, pack
        #pragma unroll
        for (int nj = 0; nj < 2; ++nj) {
            const int brow = nj * 16 + lr;
            #pragma unroll
            for (int ni = 0; ni < 2; ++ni) {
                float x[4];
                #pragma unroll
                for (int r = 0; r < 4; ++r)
                    x[r] = fmaxf(acc1[nj][ni][r]
                                 + u_c[nj] * w64v[ni][r]
                                 + yprev[nj] * wpv[ni][r], 0.0f);
                unsigned long long pk = (unsigned long long)pk2(x[0], x[1])
                                      | ((unsigned long long)pk2(x[2], x[3]) << 32);
                *(unsigned long long*)&h1[brow * H1ST + mg * 32 + ni * 16 + lk * 4] = pk;
            }
        }
        __syncthreads();   // B1: h1 + Ay col v-1 visible

        // ======== SEGMENT A: phase2(v)  ||  phase1-MFMA(v+1) ========
        // --- phase 2 (step v) ---
        f32x4 acc2[2];
        acc2[0] = (f32x4){b2c, b2c, b2c, b2c};
        acc2[1] = acc2[0];
        #pragma unroll
        for (int kt = 0; kt < 8; ++kt) {
            const f16x8 Bf = *(const f16x8*)&P2v[o_p2[kt]];
            #pragma unroll
            for (int mi = 0; mi < 2; ++mi) {
                const f16x8 Hf = *(const f16x8*)&h1[(mi * 16 + lr) * H1ST + kt * 32 + lk * 8];
                acc2[mi] = __builtin_amdgcn_mfma_f32_16x16x32_f16(Hf, Bf, acc2[mi], 0, 0, 0);
            }
        }
        #pragma unroll
        for (int mi = 0; mi < 2; ++mi) {
            float s0 = red16(fmaxf(acc2[mi][0], 0.0f) * w3c);
            float s1 = red16(fmaxf(acc2[mi][1], 0.0f) * w3c);
            float s2 = red16(fmaxf(acc2[mi][2], 0.0f) * w3c);
            float s3 = red16(fmaxf(acc2[mi][3], 0.0f) * w3c);
            if (lr == 0) {
                const int row = mi * 16 + lk * 4;
                yp[row + 0][cg] = s0;
                yp[row + 1][cg] = s1;
                yp[row + 2][cg] = s2;
                yp[row + 3][cg] = s3;
            }
        }
        // --- phase 1 MFMA for step v+1 (independent of phase 2 above) ---
        if (v < 63) {
            f32x4 nw64[2], nwp[2];
            #pragma unroll
            for (int ni = 0; ni < 2; ++ni) {
                const int dim = dimc + ni * 16;
                const f32x4 nb1 = *(const f32x4*)(b1p + dim);
                acc1[0][ni] = nb1;
                acc1[1][ni] = nb1;
                nw64[ni] = *(const f32x4*)(w64p + dim);
                const u16* wp = wpp + dim;
                nwp[ni] = (f32x4){h2f(wp[0]), h2f(wp[1]), h2f(wp[2]), h2f(wp[3])};
            }
            #pragma unroll
            for (int kt = 0; kt < 2; ++kt) {
                f16x8 Yf[2];
                #pragma unroll
                for (int nj = 0; nj < 2; ++nj)
                    Yf[nj] = *(const f16x8*)&Ay[(nj * 16 + lr) * AST + kt * 32 + lk * 8];
                #pragma unroll
                for (int ni = 0; ni < 2; ++ni) {
                    const f16x8 Wf = *(const f16x8*)&P1v[o_p1[kt][ni]];
                    #pragma unroll
                    for (int nj = 0; nj < 2; ++nj)
                        acc1[nj][ni] = __builtin_amdgcn_mfma_f32_16x16x32_f16(Wf, Yf[nj], acc1[nj][ni], 0, 0, 0);
                }
            }
            // rotate params for step v+1
            u_c[0] = Ut[urow0 + v + 1];
            u_c[1] = Ut[urow1 + v + 1];
            b2c = b2p[colc];
            w3c = W3p[colc];
            b3p = b3[v];
            w64v[0] = nw64[0]; w64v[1] = nw64[1];
            wpv[0]  = nwp[0];  wpv[1]  = nwp[1];
        }
        __syncthreads();   // B2: yp complete; h1 free for next step
    }

    // ---- y_63 from final yp, then coalesced f32 store ----
    if (w == 0 && lk == 0) {
        #pragma unroll
        for (int nj = 0; nj < 2; ++nj) {
            const int row = nj * 16 + lr;
            const f32x4 a = *(const f32x4*)&yp[row][0];
            const f32x4 b = *(const f32x4*)&yp[row][4];
            Yout[row * YOST + 63] =
                b3[63] + a[0] + a[1] + a[2] + a[3] + b[0] + b[1] + b[2] + b[3];
        }
    }
    __syncthreads();
    {
        const int row = tid >> 4, c4 = (tid & 15) * 4;
        *(float4*)(Y + (size_t)(row0 + row) * 64 + c4) = *(float4*)&Yout[row * YOST + c4];
    }
}

extern "C" void kernel_launch(void* const* d_in, const int* in_sizes, int n_in,
                              void* d_out, int out_size, void* d_ws, size_t ws_size,
                              hipStream_t stream) {
    // inputs: X, U, causal_graph, W1, b1, W2, b2, W3, b3  (X never feeds the recursion)
    const float* U  = (const float*)d_in[1];
    const int*   G  = (const int*)  d_in[2];
    const float* W1 = (const float*)d_in[3];
    const float* b1 = (const float*)d_in[4];
    const float* W2 = (const float*)d_in[5];
    const float* b2 = (const float*)d_in[6];
    const float* W3 = (const float*)d_in[7];
    const float* b3 = (const float*)d_in[8];
    float* Y = (float*)d_out;

    const size_t S1 = (size_t)64 * 64 * 256;     // u16, packed strict W1
    const size_t S2 = (size_t)64 * 256 * 128;    // u16, packed W2
    u16* P1 = (u16*)d_ws;
    u16* P2 = P1 + S1;
    u16* Wp = P2 + S2;                           // 64*256 u16 (+64*256 pad used by P1v at v=64 never loaded)

    prep_w1<<<(64 * 64 * 256) / 256, 256, 0, stream>>>(W1, G, P1);
    prep_w2<<<(64 * 256 * 128) / 256, 256, 0, stream>>>(W2, P2);
    prep_wp1<<<64, 256, 0, stream>>>(W1, G, Wp);
    sen_fused<<<BATCH / RT, 512, 0, stream>>>(U, P1, P2, Wp, W1, b1, b2, W3, b3, Y);
}

// Round 18
// 211.892 us; speedup vs baseline: 2.3149x; 1.0108x over previous
//
#include <hip/hip_runtime.h>

#define BATCH 16384
#define RT    32        // batch rows per block -> 512 blocks -> 2 blocks/CU

typedef unsigned short u16;
typedef __attribute__((ext_vector_type(8))) short short8;
typedef __attribute__((ext_vector_type(8))) _Float16 f16x8;
typedef __attribute__((ext_vector_type(4))) float f32x4;
typedef __attribute__((ext_vector_type(4))) unsigned int u32x4;

// ---------- fp16 helpers ----------
__device__ __forceinline__ u16 f2h(float x) {
    union { _Float16 h; u16 u; } c; c.h = (_Float16)x; return c.u;
}
__device__ __forceinline__ float h2f(u16 b) {
    union { u16 u; _Float16 h; } c; c.u = b; return (float)c.h;
}
__device__ __forceinline__ unsigned int pk2(float a, float b) {
    union { __attribute__((ext_vector_type(2))) __fp16 v; unsigned int u; } c;
    c.v = __builtin_amdgcn_cvt_pkrtz(a, b);
    return c.u;
}
// 16-lane sum via DPP (verified R9/R10)
__device__ __forceinline__ float red16(float x) {
    x += __builtin_bit_cast(float, __builtin_amdgcn_update_dpp(
             0, __builtin_bit_cast(int, x), 0xB1, 0xF, 0xF, true));
    x += __builtin_bit_cast(float, __builtin_amdgcn_update_dpp(
             0, __builtin_bit_cast(int, x), 0x4E, 0xF, 0xF, true));
    x += __builtin_bit_cast(float, __builtin_amdgcn_update_dpp(
             0, __builtin_bit_cast(int, x), 0x124, 0xF, 0xF, true));
    x += __builtin_bit_cast(float, __builtin_amdgcn_update_dpp(
             0, __builtin_bit_cast(int, x), 0x128, 0xF, 0xF, true));
    return x;
}

// ================= weight pre-pack kernels (single fp16) =================
// prep_w1: STRICT premask k <= v-2.
__global__ void prep_w1(const float* __restrict__ W1, const int* __restrict__ G,
                        u16* __restrict__ P) {
    int idx = blockIdx.x * 256 + threadIdx.x;   // 64*64*256 exactly
    int n = idx & 255;
    int k = (idx >> 8) & 63;
    int v = idx >> 14;
    float w = (k + 1 < v && G[k * 64 + v] > 0) ? W1[((size_t)v * 65 + k) * 256 + n] : 0.0f;
    P[(((size_t)(v * 8 + (k >> 3)) * 256 + n) << 3) + (k & 7)] = f2h(w);
}
// Pe[v][dim][8]: k0 = W1[v][64][dim] (u row), k1 = masked W1[v][v-1][dim], k2..7 = 0.
// Feeds the extra K=32 MFMA tile that replaces the VALU rank-1 updates.
__global__ void prep_we(const float* __restrict__ W1, const int* __restrict__ G,
                        u16* __restrict__ P) {
    int dim = threadIdx.x;
    int v   = blockIdx.x;
    float wu = W1[((size_t)v * 65 + 64) * 256 + dim];
    float wp = (v >= 1 && G[(v - 1) * 64 + v] > 0)
                   ? W1[((size_t)v * 65 + (v - 1)) * 256 + dim] : 0.0f;
    size_t o = ((size_t)v * 256 + dim) << 3;
    P[o + 0] = f2h(wu);
    P[o + 1] = f2h(wp);
    #pragma unroll
    for (int j = 2; j < 8; ++j) P[o + j] = 0;
}
__global__ void prep_w2(const float* __restrict__ W2, u16* __restrict__ P) {
    int idx = blockIdx.x * 256 + threadIdx.x;   // 64*256*128 exactly
    int n = idx & 127;
    int k = (idx >> 7) & 255;
    int v = idx >> 15;
    P[(((size_t)(v * 32 + (k >> 3)) * 128 + n) << 3) + (k & 7)] =
        f2h(W2[((size_t)v * 256 + k) * 128 + n]);
}

// ================= persistent fused kernel =================
// R17 structure (cross-step pipeline, 2 barriers/step, hoisted offsets,
// LDS U tile) + rank-1 terms folded into phase-1 MFMA via Pe.
#define AST   72     // Y-tile stride (u16): 144B = 16 mod 128
#define H1ST  264    // h1 stride (u16): 528B = 16 mod 128
#define YOST  68     // Yout stride (f32)
#define UST   68     // U-tile stride (f32)

__global__ __launch_bounds__(512, 4)
void sen_fused(const float* __restrict__ U,
               const u16* __restrict__ P1, const u16* __restrict__ P2,
               const u16* __restrict__ Pe,
               const float* __restrict__ b1, const float* __restrict__ b2,
               const float* __restrict__ W3, const float* __restrict__ b3,
               float* __restrict__ Y)
{
    __shared__ __attribute__((aligned(16))) u16 Ay[RT * AST];
    __shared__ __attribute__((aligned(16))) u16 h1[RT * H1ST];
    __shared__ __attribute__((aligned(16))) float yp[RT][12];  // [row][cg]+pad
    __shared__ __attribute__((aligned(16))) float Yout[RT * YOST];
    __shared__ __attribute__((aligned(16))) float Ut[RT * UST];

    const int tid  = threadIdx.x;
    const int row0 = blockIdx.x * RT;

    // zero-init Y tile + yp; stage U tile (coalesced, once)
    {
        short8 z = {0,0,0,0,0,0,0,0};
        for (int i = tid; i < (RT * AST) / 8; i += 512)
            *(short8*)&Ay[i * 8] = z;
        if (tid < RT * 12) ((float*)yp)[tid] = 0.0f;
        const int row = tid >> 4, c4 = (tid & 15) * 4;
        *(f32x4*)&Ut[row * UST + c4] =
            *(const f32x4*)(U + (size_t)(row0 + row) * 64 + c4);
    }
    __syncthreads();

    const int w  = tid >> 6, l = tid & 63;
    const int lr = l & 15,  lk = l >> 4;
    const int mg = w;   // phase 1: dim group (32 dims, W1 read once/block)
    const int cg = w;   // phase 2: col group (16 cols, W2 read once/block)

    // ---- v-invariant lane offsets (elements), computed ONCE ----
    int o_p1[2][2], o_p2[8], o_pe[2];
    #pragma unroll
    for (int kt = 0; kt < 2; ++kt)
        #pragma unroll
        for (int ni = 0; ni < 2; ++ni)
            o_p1[kt][ni] = (((kt * 4 + lk) * 256) + mg * 32 + ni * 16 + lr) << 3;
    #pragma unroll
    for (int kt = 0; kt < 8; ++kt)
        o_p2[kt] = (((kt * 4 + lk) * 128) + cg * 16 + lr) << 3;
    #pragma unroll
    for (int ni = 0; ni < 2; ++ni)
        o_pe[ni] = (mg * 32 + ni * 16 + lr) << 3;   // lk-broadcast
    const int dimc  = mg * 32 + lk * 4;   // + ni*16
    const int colc  = cg * 16 + lr;
    const int urow0 = lr * UST, urow1 = (16 + lr) * UST;

    // ---- bootstrap params for v=0; acc1 pre-initialized with b1 ----
    f32x4 acc1[2][2];
    f16x8 we[2];
    float u_c[2], b2c, w3c, b3p;
    {
        #pragma unroll
        for (int ni = 0; ni < 2; ++ni) {
            const f32x4 b1v = *(const f32x4*)(b1 + dimc + ni * 16);
            acc1[0][ni] = b1v;          // strict mask(0) is empty -> no MFMA
            acc1[1][ni] = b1v;
            we[ni] = *(const f16x8*)&Pe[o_pe[ni]];
        }
        u_c[0] = Ut[urow0];
        u_c[1] = Ut[urow1];
        b2c = b2[colc];
        w3c = W3[colc];
        b3p = 0.0f;   // y_{-1} unused (Pe k1(0)=0), just needs to be finite
    }

    #pragma unroll 1
    for (int v = 0; v < 64; ++v) {
        // per-step scalar bases (SGPR adds only)
        const u16*   P1v = P1 + (size_t)(v + 1) * 16384;   // used for v+1
        const u16*   P2v = P2 + (size_t)v * 32768;
        const u16*   Pev = Pe + (size_t)(v + 1) * 2048;
        const float* b1p = b1 + (v + 1) * 256;
        const float* b2p = b2 + (v + 1) * 128;
        const float* W3p = W3 + (v + 1) * 128;

        // ======== SEGMENT B: finish phase 1 of step v ========
        float yprev[2];
        #pragma unroll
        for (int nj = 0; nj < 2; ++nj) {
            const int row = nj * 16 + lr;
            const f32x4 a = *(const f32x4*)&yp[row][0];
            const f32x4 b = *(const f32x4*)&yp[row][4];
            yprev[nj] = b3p + a[0] + a[1] + a[2] + a[3] + b[0] + b[1] + b[2] + b[3];
        }
        if (v > 0 && w == 0 && lk == 0) {   // lazy finalize col v-1
            Ay[lr * AST + (v - 1)]        = f2h(yprev[0]);
            Ay[(16 + lr) * AST + (v - 1)] = f2h(yprev[1]);
            Yout[lr * YOST + (v - 1)]        = yprev[0];
            Yout[(16 + lr) * YOST + (v - 1)] = yprev[1];
        }
        // rank-1 terms via extra K=32 MFMA tile: B-operand nonzero only in
        // kg==0 lanes: (k0,k1) = (u, yprev); kg>0 lanes' A garbage x 0 = 0.
        #pragma unroll
        for (int nj = 0; nj < 2; ++nj) {
            const unsigned int pk_e = (lk == 0) ? pk2(u_c[nj], yprev[nj]) : 0u;
            const u32x4 t = {pk_e, 0u, 0u, 0u};
            const f16x8 Yfe = __builtin_bit_cast(f16x8, t);
            #pragma unroll
            for (int ni = 0; ni < 2; ++ni)
                acc1[nj][ni] = __builtin_amdgcn_mfma_f32_16x16x32_f16(we[ni], Yfe, acc1[nj][ni], 0, 0, 0);
        }
        // epilogue: relu + fp16 pack + h1 store (rank-1s already in acc1)
        #pragma unroll
        for (int nj = 0; nj < 2; ++nj) {
            const int brow = nj * 16 + lr;
            #pragma unroll
            for (int ni = 0; ni < 2; ++ni) {
                float x[4];
                #pragma unroll
                for (int r = 0; r < 4; ++r)
                    x[r] = fmaxf(acc1[nj][ni][r], 0.0f);
                unsigned long long pk = (unsigned long long)pk2(x[0], x[1])
                                      | ((unsigned long long)pk2(x[2], x[3]) << 32);
                *(unsigned long long*)&h1[brow * H1ST + mg * 32 + ni * 16 + lk * 4] = pk;
            }
        }
        __syncthreads();   // B1: h1 + Ay col v-1 visible

        // ======== SEGMENT A: phase2(v)  ||  phase1-MFMA(v+1) ========
        // --- phase 2 (step v) ---
        f32x4 acc2[2];
        acc2[0] = (f32x4){b2c, b2c, b2c, b2c};
        acc2[1] = acc2[0];
        #pragma unroll
        for (int kt = 0; kt < 8; ++kt) {
            const f16x8 Bf = *(const f16x8*)&P2v[o_p2[kt]];
            #pragma unroll
            for (int mi = 0; mi < 2; ++mi) {
                const f16x8 Hf = *(const f16x8*)&h1[(mi * 16 + lr) * H1ST + kt * 32 + lk * 8];
                acc2[mi] = __builtin_amdgcn_mfma_f32_16x16x32_f16(Hf, Bf, acc2[mi], 0, 0, 0);
            }
        }
        #pragma unroll
        for (int mi = 0; mi < 2; ++mi) {
            float s0 = red16(fmaxf(acc2[mi][0], 0.0f) * w3c);
            float s1 = red16(fmaxf(acc2[mi][1], 0.0f) * w3c);
            float s2 = red16(fmaxf(acc2[mi][2], 0.0f) * w3c);
            float s3 = red16(fmaxf(acc2[mi][3], 0.0f) * w3c);
            if (lr == 0) {
                const int row = mi * 16 + lk * 4;
                yp[row + 0][cg] = s0;
                yp[row + 1][cg] = s1;
                yp[row + 2][cg] = s2;
                yp[row + 3][cg] = s3;
            }
        }
        // --- phase 1 MFMA for step v+1 (independent of phase 2 above) ---
        if (v < 63) {
            #pragma unroll
            for (int ni = 0; ni < 2; ++ni) {
                const f32x4 nb1 = *(const f32x4*)(b1p + dimc + ni * 16);
                acc1[0][ni] = nb1;
                acc1[1][ni] = nb1;
            }
            #pragma unroll
            for (int kt = 0; kt < 2; ++kt) {
                f16x8 Yf[2];
                #pragma unroll
                for (int nj = 0; nj < 2; ++nj)
                    Yf[nj] = *(const f16x8*)&Ay[(nj * 16 + lr) * AST + kt * 32 + lk * 8];
                #pragma unroll
                for (int ni = 0; ni < 2; ++ni) {
                    const f16x8 Wf = *(const f16x8*)&P1v[o_p1[kt][ni]];
                    #pragma unroll
                    for (int nj = 0; nj < 2; ++nj)
                        acc1[nj][ni] = __builtin_amdgcn_mfma_f32_16x16x32_f16(Wf, Yf[nj], acc1[nj][ni], 0, 0, 0);
                }
            }
            // rotate params for step v+1
            we[0] = *(const f16x8*)&Pev[o_pe[0]];
            we[1] = *(const f16x8*)&Pev[o_pe[1]];
            u_c[0] = Ut[urow0 + v + 1];
            u_c[1] = Ut[urow1 + v + 1];
            b2c = b2p[colc];
            w3c = W3p[colc];
            b3p = b3[v];
        }
        __syncthreads();   // B2: yp complete; h1 free for next step
    }

    // ---- y_63 from final yp, then coalesced f32 store ----
    if (w == 0 && lk == 0) {
        #pragma unroll
        for (int nj = 0; nj < 2; ++nj) {
            const int row = nj * 16 + lr;
            const f32x4 a = *(const f32x4*)&yp[row][0];
            const f32x4 b = *(const f32x4*)&yp[row][4];
            Yout[row * YOST + 63] =
                b3[63] + a[0] + a[1] + a[2] + a[3] + b[0] + b[1] + b[2] + b[3];
        }
    }
    __syncthreads();
    {
        const int row = tid >> 4, c4 = (tid & 15) * 4;
        *(float4*)(Y + (size_t)(row0 + row) * 64 + c4) = *(float4*)&Yout[row * YOST + c4];
    }
}

extern "C" void kernel_launch(void* const* d_in, const int* in_sizes, int n_in,
                              void* d_out, int out_size, void* d_ws, size_t ws_size,
                              hipStream_t stream) {
    // inputs: X, U, causal_graph, W1, b1, W2, b2, W3, b3  (X never feeds the recursion)
    const float* U  = (const float*)d_in[1];
    const int*   G  = (const int*)  d_in[2];
    const float* W1 = (const float*)d_in[3];
    const float* b1 = (const float*)d_in[4];
    const float* W2 = (const float*)d_in[5];
    const float* b2 = (const float*)d_in[6];
    const float* W3 = (const float*)d_in[7];
    const float* b3 = (const float*)d_in[8];
    float* Y = (float*)d_out;

    const size_t S1 = (size_t)64 * 64 * 256;     // u16, packed strict W1
    const size_t S2 = (size_t)64 * 256 * 128;    // u16, packed W2
    u16* P1 = (u16*)d_ws;
    u16* P2 = P1 + S1;
    u16* Pe = P2 + S2;                           // 64*256*8 u16 (256 KB)

    prep_w1<<<(64 * 64 * 256) / 256, 256, 0, stream>>>(W1, G, P1);
    prep_w2<<<(64 * 256 * 128) / 256, 256, 0, stream>>>(W2, P2);
    prep_we<<<64, 256, 0, stream>>>(W1, G, Pe);
    sen_fused<<<BATCH / RT, 512, 0, stream>>>(U, P1, P2, Pe, b1, b2, W3, b3, Y);
}